// Round 9
// baseline (709.895 us; speedup 1.0000x reference)
//
#include <hip/hip_runtime.h>
#include <math.h>

#define NN 65536   // edges
#define KTOP 64

typedef const __attribute__((address_space(1))) void* gas_ptr;
typedef __attribute__((address_space(3))) void* las_ptr;

__device__ __forceinline__ void gload_lds16(const float* g, float* lds) {
    __builtin_amdgcn_global_load_lds((gas_ptr)g, (las_ptr)lds, 16, 0, 0);
}

// ---------------------------------------------------------------------------
// Kernel 1 v2: G = Wq^T @ Wk (512x512). 64 blocks of 64x64 tiles, 256 threads
// (16x16), 4x4 outputs each, float4 LDS traffic, register-prefetched staging.
// Also emits Gimg: 16 pre-swizzled 64x64 tiles of the Ghh quadrant laid out so
// k_edge can stage them with linear global_load_lds.
//   tile T = (m>>6)*4 + (n>>6); r=m&63; c=n&63;
//   x = c ^ ((r&7)<<3) ^ (((r>>5)&1)<<2);  Gimg[T*4096 + r*64 + x] = G[m][n]
// ---------------------------------------------------------------------------
__global__ void k_gemm_G(const float* __restrict__ Wq, const float* __restrict__ Wk,
                         float* __restrict__ G, float* __restrict__ Gimg)
{
    __shared__ __align__(16) float As[32][68];
    __shared__ __align__(16) float Bs[32][68];
    const int t  = threadIdx.x;
    const int tm = t >> 4, tn = t & 15;
    const int m0 = (blockIdx.x >> 3) * 64, n0 = (blockIdx.x & 7) * 64;
    const int sr = t >> 3, sc = (t & 7) * 8;

    float4 q0, q1, v0, v1;
    {
        const float* wq = Wq + (size_t)sr * 512 + m0 + sc;
        const float* wk = Wk + (size_t)sr * 512 + n0 + sc;
        q0 = *(const float4*)wq; q1 = *(const float4*)(wq + 4);
        v0 = *(const float4*)wk; v1 = *(const float4*)(wk + 4);
    }
    float acc[4][4] = {};
    for (int k0 = 0; k0 < 512; k0 += 32) {
        __syncthreads();                       // previous compute done
        *(float4*)&As[sr][sc]     = q0; *(float4*)&As[sr][sc + 4] = q1;
        *(float4*)&Bs[sr][sc]     = v0; *(float4*)&Bs[sr][sc + 4] = v1;
        __syncthreads();
        if (k0 + 32 < 512) {                   // prefetch next k-slab
            const float* wq = Wq + (size_t)(k0 + 32 + sr) * 512 + m0 + sc;
            const float* wk = Wk + (size_t)(k0 + 32 + sr) * 512 + n0 + sc;
            q0 = *(const float4*)wq; q1 = *(const float4*)(wq + 4);
            v0 = *(const float4*)wk; v1 = *(const float4*)(wk + 4);
        }
        #pragma unroll 8
        for (int k = 0; k < 32; ++k) {
            float4 a = *(const float4*)&As[k][tm * 4];
            float4 b = *(const float4*)&Bs[k][tn * 4];
            acc[0][0] += a.x*b.x; acc[0][1] += a.x*b.y; acc[0][2] += a.x*b.z; acc[0][3] += a.x*b.w;
            acc[1][0] += a.y*b.x; acc[1][1] += a.y*b.y; acc[1][2] += a.y*b.z; acc[1][3] += a.y*b.w;
            acc[2][0] += a.z*b.x; acc[2][1] += a.z*b.y; acc[2][2] += a.z*b.z; acc[2][3] += a.z*b.w;
            acc[3][0] += a.w*b.x; acc[3][1] += a.w*b.y; acc[3][2] += a.w*b.z; acc[3][3] += a.w*b.w;
        }
    }
    #pragma unroll
    for (int im = 0; im < 4; ++im) {
        int m = m0 + tm * 4 + im;
        float4 o; o.x = acc[im][0]; o.y = acc[im][1]; o.z = acc[im][2]; o.w = acc[im][3];
        *(float4*)&G[(size_t)m * 512 + n0 + tn * 4] = o;
    }
    if (m0 < 256 && n0 < 256) {
        #pragma unroll
        for (int im = 0; im < 4; ++im) {
            int m = m0 + tm * 4 + im;
            int r = m & 63;
            #pragma unroll
            for (int in = 0; in < 4; ++in) {
                int n = n0 + tn * 4 + in;
                int T = ((m >> 6) << 2) | (n >> 6);
                int x = (n & 63) ^ ((r & 7) << 3) ^ (((r >> 5) & 1) << 2);
                Gimg[T * 4096 + r * 64 + x] = acc[im][in];
            }
        }
    }
}

// ---------------------------------------------------------------------------
// Kernel 2 v2: per-batch vectors bL, bR, cB. float4 G reads in the w-loops.
// ---------------------------------------------------------------------------
__global__ void k_batch(const float* __restrict__ qs, const float* __restrict__ qr,
                        const float* __restrict__ G,
                        float* __restrict__ bL, float* __restrict__ bR, float* __restrict__ cB)
{
    const int e = blockIdx.x, t = threadIdx.x;
    __shared__ __align__(16) float qcat[256];
    __shared__ float whi[256];
    __shared__ float red[256];
    qcat[t] = (t < 128) ? qs[(size_t)e * 128 + t] : qr[(size_t)e * 128 + (t - 128)];
    __syncthreads();
    float w0 = 0.f, w1 = 0.f;
    for (int r4 = 0; r4 < 64; ++r4) {
        float4 g0 = *(const float4*)&G[(size_t)t * 512 + 256 + r4 * 4];
        float4 g1 = *(const float4*)&G[(size_t)(t + 256) * 512 + 256 + r4 * 4];
        float4 q  = *(const float4*)&qcat[r4 * 4];
        w0 += g0.x*q.x + g0.y*q.y + g0.z*q.z + g0.w*q.w;
        w1 += g1.x*q.x + g1.y*q.y + g1.z*q.z + g1.w*q.w;
    }
    bL[(size_t)e * 256 + t] = w0;
    whi[t] = w1;
    float v = 0.f;
    for (int r = 0; r < 256; ++r)          // coalesced across t
        v += qcat[r] * G[(size_t)(256 + r) * 512 + t];
    bR[(size_t)e * 256 + t] = v;
    __syncthreads();
    red[t] = qcat[t] * whi[t];
    __syncthreads();
    for (int s = 128; s > 0; s >>= 1) {
        if (t < s) red[t] += red[t + s];
        __syncthreads();
    }
    if (t == 0) cB[e] = red[0];
}

// ---------------------------------------------------------------------------
// Kernel 3 v4: per-edge logits. 64 edges/block, 256 threads.
// T3 2-phase pipeline: Bt double-buffered [2][64][64]; 16 phases (kt2 0..3 x
// ct 0..3); next tile's global_load_lds + this phase's rpre issued at phase
// START, drained by the single end-of-phase barrier (latency under FMA).
// At column-swizzled with ((k>>3)&15)<<2 to kill the bL 16-way conflict.
// ---------------------------------------------------------------------------
#define FMAROW(J, AX) \
    acc[J][0] += AX * b0.x; acc[J][1] += AX * b0.y; \
    acc[J][2] += AX * b0.z; acc[J][3] += AX * b0.w; \
    acc[J][4] += AX * b1.x; acc[J][5] += AX * b1.y; \
    acc[J][6] += AX * b1.z; acc[J][7] += AX * b1.w;

__launch_bounds__(256, 1)
__global__ void k_edge(const float* __restrict__ vnr, const float* __restrict__ rel,
                       const int* __restrict__ edges, const float* __restrict__ Gimg,
                       const float* __restrict__ bL, const float* __restrict__ bR,
                       const float* __restrict__ cB, float* __restrict__ logits)
{
    __shared__ __align__(16) float At[128][64];
    __shared__ __align__(16) float Bt[2][64][64];
    __shared__ __align__(16) float bLs[256];
    __shared__ __align__(16) float bRs[256];
    __shared__ int jL[64];

    const int t  = threadIdx.x;
    const int n0 = blockIdx.x * 64;
    const int eg = n0 >> 10;

    const int kh = t & 1;
    const int g  = (t >> 1) & 7;
    const int e0 = 4 * (t >> 4);
    const int eS = t & 63, w = t >> 6;          // w uniform per wave
    const int ldsOfs = w * 256;                 // wave-uniform gload dest offset

    if (t < 64) jL[t] = edges[(size_t)(n0 + t) * 8 + 7];
    bLs[t] = bL[(size_t)eg * 256 + t];
    bRs[t] = bR[(size_t)eg * 256 + t];

    // ---- stage Bt tile 0 (async) + At (vnr, col-swizzled transposed store)
    {
        const float* gsrc = Gimg + t * 4;
        float* ldst = &Bt[0][0][0] + ldsOfs;
        #pragma unroll
        for (int q = 0; q < 4; ++q)
            gload_lds16(gsrc + q * 1024, ldst + q * 1024);
    }
    {
        int seg = edges[(size_t)(n0 + eS) * 8 + 6];
        const float* src = vnr + (size_t)seg * 128 + w * 32;
        float4 a[8];
        #pragma unroll
        for (int q = 0; q < 8; ++q) a[q] = *(const float4*)(src + q * 4);
        #pragma unroll
        for (int q = 0; q < 8; ++q) {
            int k = w * 32 + q * 4;
            int col = eS ^ (((k >> 3) & 15) << 2);
            At[k + 0][col] = a[q].x; At[k + 1][col] = a[q].y;
            At[k + 2][col] = a[q].z; At[k + 3][col] = a[q].w;
        }
    }
    __syncthreads();                            // everything staged & visible

    double s[4] = {0.0, 0.0, 0.0, 0.0};

    // ---- bL partial, k 0..127  (col = e0 ^ ((t&15)<<2), conflict-reduced)
    {
        const int kb = (t & 15) * 8;
        const int colA = e0 ^ ((t & 15) << 2);
        float la[4] = {0.f, 0.f, 0.f, 0.f};
        #pragma unroll
        for (int i = 0; i < 8; ++i) {
            float bl = bLs[kb + i];
            float4 a = *(const float4*)&At[kb + i][colA];
            la[0] += a.x * bl; la[1] += a.y * bl;
            la[2] += a.z * bl; la[3] += a.w * bl;
        }
        #pragma unroll
        for (int j = 0; j < 4; ++j) s[j] += (double)la[j];
    }

    int cur = 0;
    float4 arel[8];

    #pragma unroll 1
    for (int ph = 0; ph < 16; ++ph) {
        const int kt2 = ph >> 2, ct = ph & 3;
        // ---- issue next Bt tile into the other buffer (hidden under FMA)
        if (ph < 15) {
            const float* gsrc = Gimg + (ph + 1) * 4096 + t * 4;
            float* ldst = &Bt[cur ^ 1][0][0] + ldsOfs;
            #pragma unroll
            for (int q = 0; q < 4; ++q)
                gload_lds16(gsrc + q * 1024, ldst + q * 1024);
        }
        // ---- issue this phase's Rh rows (consumed in epilogue, post-FMA)
        float4 rpre[8];
        #pragma unroll
        for (int j = 0; j < 4; ++j) {
            const float* rp = (ct < 2)
                ? (vnr + (size_t)jL[e0 + j] * 128 + ct * 64 + g * 8)
                : (rel + (size_t)(n0 + e0 + j) * 128 + (ct - 2) * 64 + g * 8);
            rpre[2 * j]     = *(const float4*)(rp);
            rpre[2 * j + 1] = *(const float4*)(rp + 4);
        }
        // ---- issue At restage loads one phase early (hidden under ph7 FMA)
        if (ph == 7) {
            const float* src = rel + (size_t)(n0 + eS) * 128 + w * 32;
            #pragma unroll
            for (int q = 0; q < 8; ++q) arel[q] = *(const float4*)(src + q * 4);
        }
        // ---- 64(e) x 64(c) x 32(k-half) FMA tile on Bt[cur]
        float acc[4][8] = {};
        const int cb0   = (g * 8) ^ (kh << 2);
        const int rbase = (kt2 & 1) * 64 + kh * 32;
        const float* btb = &Bt[cur][0][0] + kh * 32 * 64;
        #pragma unroll
        for (int m = 0; m < 4; ++m) {
            const int colA = e0 ^ ((((rbase >> 3) + m) & 15) << 2);
            #pragma unroll
            for (int jj = 0; jj < 8; ++jj) {
                const int i = m * 8 + jj;
                float4 a  = *(const float4*)&At[rbase + i][colA];
                const int cb = cb0 ^ (jj << 3);
                float4 b0 = *(const float4*)(btb + i * 64 + cb);
                float4 b1 = *(const float4*)(btb + i * 64 + (cb ^ 4));
                FMAROW(0, a.x) FMAROW(1, a.y) FMAROW(2, a.z) FMAROW(3, a.w)
            }
        }
        // ---- epilogue: acc . Rh (+ bR term once: kt2==0 && kh==0)
        const int cbase = ct * 64 + g * 8;
        const bool doBR = (kt2 == 0) && (kh == 0);
        float4 br0, br1;
        if (doBR) {
            br0 = *(const float4*)&bRs[cbase];
            br1 = *(const float4*)&bRs[cbase + 4];
        }
        #pragma unroll
        for (int j = 0; j < 4; ++j) {
            float4 ra = rpre[2 * j], rb = rpre[2 * j + 1];
            float d = acc[j][0]*ra.x + acc[j][1]*ra.y + acc[j][2]*ra.z + acc[j][3]*ra.w
                    + acc[j][4]*rb.x + acc[j][5]*rb.y + acc[j][6]*rb.z + acc[j][7]*rb.w;
            if (doBR) {
                d += ra.x*br0.x + ra.y*br0.y + ra.z*br0.z + ra.w*br0.w
                   + rb.x*br1.x + rb.y*br1.y + rb.z*br1.z + rb.w*br1.w;
            }
            s[j] += (double)d;
        }
        __syncthreads();                        // next Bt staged; Bt[cur] reads done
        if (ph == 7) {                          // restage At with rel rows
            #pragma unroll
            for (int q = 0; q < 8; ++q) {
                int k = w * 32 + q * 4;
                int col = eS ^ (((k >> 3) & 15) << 2);
                At[k + 0][col] = arel[q].x; At[k + 1][col] = arel[q].y;
                At[k + 2][col] = arel[q].z; At[k + 3][col] = arel[q].w;
            }
            __syncthreads();
            // bL partial, k 128..255
            const int kb = (t & 15) * 8;
            const int colA = e0 ^ ((t & 15) << 2);
            float la[4] = {0.f, 0.f, 0.f, 0.f};
            #pragma unroll
            for (int i = 0; i < 8; ++i) {
                float bl = bLs[128 + kb + i];
                float4 a = *(const float4*)&At[kb + i][colA];
                la[0] += a.x * bl; la[1] += a.y * bl;
                la[2] += a.z * bl; la[3] += a.w * bl;
            }
            #pragma unroll
            for (int j = 0; j < 4; ++j) s[j] += (double)la[j];
        }
        cur ^= 1;
    }
    // ---- reduce over (kh, g) = lane bits 0..3
    #pragma unroll
    for (int m = 1; m < 16; m <<= 1) {
        #pragma unroll
        for (int j = 0; j < 4; ++j) s[j] += __shfl_xor(s[j], m, 64);
    }
    if ((t & 15) == 0) {
        float base = cB[eg];
        #pragma unroll
        for (int j = 0; j < 4; ++j)
            logits[n0 + e0 + j] = (float)s[j] + base;
    }
}

// ---------------------------------------------------------------------------
// Kernel 4: deterministic fused segment softmax (seg sorted -> contiguous runs)
// ---------------------------------------------------------------------------
__global__ void k_segstats(const int* __restrict__ edges, const float* __restrict__ logits,
                           const float* __restrict__ score,
                           float* __restrict__ soft, float* __restrict__ tsc)
{
    int n = blockIdx.x * 256 + threadIdx.x;
    if (n >= NN) return;
    int s = edges[(size_t)n * 8 + 6];
    if (n > 0 && edges[(size_t)(n - 1) * 8 + 6] == s) return;   // not a run start
    float m = -INFINITY;
    int k = n;
    while (k < NN && edges[(size_t)k * 8 + 6] == s) {
        m = fmaxf(m, logits[k]);
        ++k;
    }
    float d = 0.f;
    for (int q = n; q < k; ++q) d += expf(logits[q] - m);
    float sc = score[s];
    for (int q = n; q < k; ++q) {
        float so = expf(logits[q] - m) / d;
        soft[q] = so;
        tsc[q]  = so * sc;
    }
}

// ---------------------------------------------------------------------------
// Kernel 5: register bitonic sort on tscore (shfl <64, LDS >=64),
// descending stable by index. 64 blocks x 1024 threads.
// ---------------------------------------------------------------------------
__global__ void k_topk(const int* __restrict__ edges, const float* __restrict__ soft,
                       const float* __restrict__ tsc, float* __restrict__ out)
{
    __shared__ float vsh[1024];
    __shared__ int   ish[1024];
    const int r = blockIdx.x, t = threadIdx.x;
    const int n = r * 1024 + t;
    float v = tsc[n];
    int idx = t;
    for (int size = 2; size <= 1024; size <<= 1) {
        for (int stride = size >> 1; stride > 0; stride >>= 1) {
            float v2; int i2;
            if (stride < 64) {
                v2 = __shfl_xor(v, stride, 64);
                i2 = __shfl_xor(idx, stride, 64);
            } else {
                __syncthreads();
                vsh[t] = v; ish[t] = idx;
                __syncthreads();
                v2 = vsh[t ^ stride]; i2 = ish[t ^ stride];
            }
            bool before = (v > v2) || (v == v2 && idx < i2);   // desc, stable
            bool desc   = ((t & size) == 0);
            bool keep   = ((t & stride) == 0) ? (before == desc) : (before != desc);
            if (!keep) { v = v2; idx = i2; }
        }
    }
    if (t < KTOP) {
        int orig = r * 1024 + idx;
        int o = r * KTOP + t;
        out[o]        = v;                       // pruned_target_score
        out[4096 + o] = soft[orig];              // pruned_softmax
        #pragma unroll
        for (int q = 0; q < 8; ++q)              // pruned_edges
            out[8192 + (size_t)o * 8 + q] = (float)edges[(size_t)orig * 8 + q];
        out[40960 + o] = (float)orig;            // orig_indices
    }
}

// ---------------------------------------------------------------------------
extern "C" void kernel_launch(void* const* d_in, const int* in_sizes, int n_in,
                              void* d_out, int out_size, void* d_ws, size_t ws_size,
                              hipStream_t stream)
{
    (void)in_sizes; (void)n_in; (void)out_size; (void)ws_size;
    const float* score = (const float*)d_in[0];
    const float* vnr   = (const float*)d_in[1];
    const float* rel   = (const float*)d_in[2];
    const float* qs    = (const float*)d_in[3];
    const float* qr    = (const float*)d_in[4];
    const float* Wq    = (const float*)d_in[5];
    const float* Wk    = (const float*)d_in[6];
    const int*   edges = (const int*)  d_in[7];
    float* out = (float*)d_out;

    float* ws     = (float*)d_ws;
    float* G      = ws;                 // 512*512          = 262144
    float* Gimg   = G      + 262144;    // 16*4096          = 65536
    float* bL     = Gimg   + 65536;     // 64*256
    float* bR     = bL     + 16384;     // 64*256
    float* cB     = bR     + 16384;     // 64
    float* logits = cB     + 64;        // 65536
    float* soft   = logits + 65536;     // 65536
    float* tsc    = soft   + 65536;     // 65536

    k_gemm_G  <<<64, 256, 0, stream>>>(Wq, Wk, G, Gimg);
    k_batch   <<<64, 256, 0, stream>>>(qs, qr, G, bL, bR, cB);
    k_edge    <<<1024, 256, 0, stream>>>(vnr, rel, edges, Gimg, bL, bR, cB, logits);
    k_segstats<<<256, 256, 0, stream>>>(edges, logits, score, soft, tsc);
    k_topk    <<<64, 1024, 0, stream>>>(edges, soft, tsc, out);
}